// Round 1
// baseline (191.457 us; speedup 1.0000x reference)
//
#include <hip/hip_runtime.h>

// NeRF positional encoding: x[rows,4] -> out[rows,768]
// Per row: 64-float block [sin/cos of 2^l*pi*x_c, l=0..7, c=0..3], tiled 12x.
// Write-BW bound: 201 MB out / 1 MB in. One wave per row; lane i owns float4
// chunk (i&15) of the block, computes 2 sincos once, stores it 3x per row
// (3 x 64-lane wave-strided float4 stores = 192 chunks = 768 floats).
__global__ __launch_bounds__(256) void nerf_pe_kernel(const float* __restrict__ x,
                                                      float* __restrict__ out,
                                                      int rows) {
    const int tid  = blockIdx.x * blockDim.x + threadIdx.x;
    const int row  = tid >> 6;      // one 64-lane wave per row
    const int lane = tid & 63;
    if (row >= rows) return;

    // chunk k = lane & 15 within the 64-float block:
    //   freq index l = k >> 1, coord base c = 2*(k & 1)
    const int   l = (lane & 15) >> 1;
    const int   c = (lane & 1) << 1;
    const float f = 3.14159265358979f * (float)(1 << l);   // 2^l * pi (exact pow2 scale)

    const float x0 = x[row * 4 + c];
    const float x1 = x[row * 4 + c + 1];
    const float a0 = f * x0;
    const float a1 = f * x1;

    float4 v;
    v.x = __sinf(a0);   // v_sin_f32; max |a|/2pi = 64 rev, in HW range
    v.y = __cosf(a0);
    v.z = __sinf(a1);
    v.w = __cosf(a1);

    // row = 192 float4 chunks; this lane's value is valid at chunk
    // j = it*64 + lane for it = 0..2 (since j % 16 == lane % 16).
    float4* o = reinterpret_cast<float4*>(out + (size_t)row * 768) + lane;
    o[0]   = v;
    o[64]  = v;
    o[128] = v;
}

extern "C" void kernel_launch(void* const* d_in, const int* in_sizes, int n_in,
                              void* d_out, int out_size, void* d_ws, size_t ws_size,
                              hipStream_t stream) {
    const float* x   = (const float*)d_in[0];
    float*       out = (float*)d_out;
    const int rows    = in_sizes[0] / 4;          // 65536
    const int threads = rows * 64;                // one wave per row
    const int blocks  = (threads + 255) / 256;
    nerf_pe_kernel<<<blocks, 256, 0, stream>>>(x, out, rows);
}